// Round 4
// baseline (285.218 us; speedup 1.0000x reference)
//
#include <hip/hip_runtime.h>
#include <math.h>

#define A_TOT 8400
#define B_N   2
#define T_N   100
#define C_N   80
#define E_N   32
#define MH_N  64
#define MW_N  64
#define ROW_N 8363          // 4 + 80 + 85 + 4096 + 4098
#define NROWS (B_N*A_TOT)   // 16800
#define EPSF  1e-9f
#define PARAM_STRIDE 12

// Single emitted copy shared by k_topk and k_assign -> bitwise-identical tmat.
__device__ __attribute__((noinline)) float2 tmat_eval(
    float gx1, float gy1, float gx2, float gy2,
    float ax,  float ay,
    float px1, float py1, float px2, float py2,
    float cl) {
  float ix1 = fmaxf(gx1,px1), iy1 = fmaxf(gy1,py1);
  float ix2 = fminf(gx2,px2), iy2 = fminf(gy2,py2);
  float inter = fmaxf(ix2-ix1,0.f) * fmaxf(iy2-iy1,0.f);
  float wg = gx2-gx1, hg = gy2-gy1, wp = px2-px1, hp = py2-py1;
  float uni = wg*hg + wp*hp - inter + EPSF;
  float iou = inter / uni;
  float cw = fmaxf(gx2,px2) - fminf(gx1,px1);
  float ch = fmaxf(gy2,py2) - fminf(gy1,py1);
  float c2 = cw*cw + ch*ch + EPSF;
  float dx = gx1+gx2-px1-px2, dy = gy1+gy2-py1-py2;
  float rho2 = (dx*dx + dy*dy) * 0.25f;
  float da = atanf(wg/(hg+EPSF)) - atanf(wp/(hp+EPSF));
  float v  = 0.4052847345693511f * da * da;     // 4/pi^2
  float alpha = v / (1.f - iou + v + EPSF);
  float ciou = iou - rho2/c2 - alpha*v;
  float iouc = fminf(fmaxf(ciou, 0.f), 1.f);

  float tm = 0.f;
  if (ax > gx1 && ay > gy1 && ax < gx2 && ay < gy2) {   // strict grid mask
    float cp = 1.f / (1.f + expf(-cl));
    float i2 = iouc * iouc;
    tm = i2*i2*i2 * sqrtf(cp);                 // iou^6 * cls^0.5
  }
  return make_float2(tm, iouc);
}

// ---- kernel 1: per (b,t) block: kth (10th largest tmat), max tmat, max iou
__global__ __launch_bounds__(256) void k_topk(
    const float* __restrict__ cls_logits, const float* __restrict__ pred_boxes,
    const float* __restrict__ target_bbox, const int* __restrict__ target_cls,
    const float* __restrict__ anchors,
    float* __restrict__ kth, float* __restrict__ maxt, float* __restrict__ maxiou) {
  int bt = blockIdx.x;
  int b  = bt / T_N;
  int tid = threadIdx.x;
  __shared__ float vals[A_TOT];
  __shared__ float red[256];
  __shared__ int   sidx;

  float gx1 = target_bbox[bt*4+0], gy1 = target_bbox[bt*4+1];
  float gx2 = target_bbox[bt*4+2], gy2 = target_bbox[bt*4+3];
  int   tc  = target_cls[bt];

  float lm = 0.f, li = 0.f;                    // tmat,iou_clipped are >= 0
  for (int a = tid; a < A_TOT; a += 256) {
    float4 pb = *(const float4*)(pred_boxes + ((size_t)(b*A_TOT+a))*4);
    float ax = anchors[a*2+0], ay = anchors[a*2+1];
    float cl = cls_logits[((size_t)(b*A_TOT+a))*C_N + tc];
    float2 r = tmat_eval(gx1,gy1,gx2,gy2, ax,ay, pb.x,pb.y,pb.z,pb.w, cl);
    vals[a] = r.x;
    lm = fmaxf(lm, r.x);
    li = fmaxf(li, r.y);
  }
  red[tid] = lm; __syncthreads();
  for (int s = 128; s > 0; s >>= 1) { if (tid < s) red[tid] = fmaxf(red[tid], red[tid+s]); __syncthreads(); }
  if (tid == 0) maxt[bt] = red[0];
  __syncthreads();
  red[tid] = li; __syncthreads();
  for (int s = 128; s > 0; s >>= 1) { if (tid < s) red[tid] = fmaxf(red[tid], red[tid+s]); __syncthreads(); }
  if (tid == 0) maxiou[bt] = red[0];

  float cur = 0.f;
  for (int k = 0; k < 10; k++) {
    __syncthreads();
    float l = -1e30f;
    for (int i = tid; i < A_TOT; i += 256) l = fmaxf(l, vals[i]);
    red[tid] = l; __syncthreads();
    for (int s = 128; s > 0; s >>= 1) { if (tid < s) red[tid] = fmaxf(red[tid], red[tid+s]); __syncthreads(); }
    float m = red[0];
    if (tid == 0) sidx = 0x7fffffff;
    __syncthreads();
    for (int i = tid; i < A_TOT; i += 256) if (vals[i] == m) atomicMin(&sidx, i);
    __syncthreads();
    if (tid == 0 && sidx != 0x7fffffff) vals[sidx] = -1e30f;  // remove ONE instance
    cur = m;
  }
  if (tid == 0) kth[bt] = cur;
}

// ---- kernel 2: per (b,a): assignment + per-row params ---------------------
__global__ __launch_bounds__(256) void k_assign(
    const float* __restrict__ cls_logits, const float* __restrict__ pred_boxes,
    const float* __restrict__ target_bbox, const int* __restrict__ target_cls,
    const float* __restrict__ anchors, const float* __restrict__ scalers,
    const float* __restrict__ kth,
    const float* __restrict__ maxt, const float* __restrict__ maxiou,
    float* __restrict__ params) {
  int b   = blockIdx.y;
  int tid = threadIdx.x;
  int a   = blockIdx.x * 256 + tid;
  __shared__ float tbb[T_N*4];
  __shared__ int   tcs[T_N];
  __shared__ float kths[T_N];
  if (tid < T_N) { tcs[tid] = target_cls[b*T_N+tid]; kths[tid] = kth[b*T_N+tid]; }
  for (int i = tid; i < T_N*4; i += 256) tbb[i] = target_bbox[b*T_N*4 + i];
  __syncthreads();
  if (a >= A_TOT) return;

  float ax = anchors[a*2+0], ay = anchors[a*2+1];
  float4 pb = *(const float4*)(pred_boxes + ((size_t)(b*A_TOT+a))*4);
  const float* crow = cls_logits + ((size_t)(b*A_TOT+a))*C_N;

  float best = 0.f; int u = 0; int any = 0;
  for (int t = 0; t < T_N; t++) {
    float2 r = tmat_eval(tbb[4*t],tbb[4*t+1],tbb[4*t+2],tbb[4*t+3],
                         ax,ay, pb.x,pb.y,pb.z,pb.w, crow[tcs[t]]);
    float v = r.x;
    if (v > 0.f && v >= kths[t]) {            // topk_targets condition
      any = 1;
      if (v > best) { best = v; u = t; }      // argmax, first occurrence
    }
  }
  int bu = b*T_N + u;
  float ng = any ? best / (maxt[bu] + EPSF) * maxiou[bu] : 0.f;
  float tb0 = tbb[4*u], tb1 = tbb[4*u+1], tb2 = tbb[4*u+2], tb3 = tbb[4*u+3];
  float s = scalers[a];
  float area = (tb2-tb0)*(tb3-tb1) / (640.f*640.f);

  int row = b*A_TOT + a;
  float* pp = params + (size_t)row * PARAM_STRIDE;
  pp[0] = tb0; pp[1] = tb1; pp[2] = tb2; pp[3] = tb3;
  pp[4] = any ? 1.f : 0.f; pp[5] = ng; pp[6] = s; pp[7] = area;
  pp[8] = __int_as_float(u); pp[9] = __int_as_float(tcs[u]);
  pp[10] = 0.f; pp[11] = 0.f;
}

// ---- value of output element `pos` within row `row` -----------------------
__device__ __forceinline__ float val_at(
    unsigned pos, unsigned row, int b,
    const float* __restrict__ cls_logits, const float* __restrict__ pred_boxes,
    const float* __restrict__ mask_embs,  const float* __restrict__ protos,
    const float* __restrict__ t_masks,    const float* __restrict__ params,
    float4 P0, float4 P1) {
  if (pos < 84u) {
    if (pos < 4u) return pred_boxes[(size_t)row*4 + pos] / P1.z;
    return cls_logits[(size_t)row*C_N + (pos-4u)];
  }
  if (pos < 169u) {
    if (pos < 88u) {
      float t = (pos==84u)?P0.x:((pos==85u)?P0.y:((pos==86u)?P0.z:P0.w));
      return t / P1.z;
    }
    if (pos == 88u) return P1.x;
    int c = (int)pos - 89;
    int ct = __float_as_int(params[(size_t)row*PARAM_STRIDE + 9]);
    return (P1.x > 0.5f && c == ct) ? P1.y : 0.f;
  }
  if (pos < 4265u) {                               // seg_pred
    if (P1.x <= 0.5f) return 0.f;
    unsigned p = pos - 169u; int h = p >> 6, w = p & 63;
    float fh = (float)h, fw = (float)w;
    float x1s = P0.x*0.1f, y1s = P0.y*0.1f, x2s = P0.z*0.1f, y2s = P0.w*0.1f;
    if (!(fh >= y1s && fh < y2s && fw >= x1s && fw < x2s)) return 0.f;
    const float* pr = protos   + ((size_t)((b*MH_N + h)*MW_N + w)) * E_N;
    const float* se = mask_embs + (size_t)row * E_N;
    float acc = 0.f;
    #pragma unroll
    for (int e = 0; e < E_N; e++) acc += se[e] * pr[e];
    return 1.f / (1.f + expf(-acc));
  }
  if (pos == 4265u) return P1.w;
  if (pos == 4266u) return P1.x;
  // align_seg
  if (P1.x <= 0.5f) return 0.f;
  unsigned p = pos - 4267u; int h = p >> 6, w = p & 63;
  float fh = (float)h, fw = (float)w;
  float x1s = P0.x*0.1f, y1s = P0.y*0.1f, x2s = P0.z*0.1f, y2s = P0.w*0.1f;
  if (!(fh >= y1s && fh < y2s && fw >= x1s && fw < x2s)) return 0.f;
  int u = __float_as_int(params[(size_t)row*PARAM_STRIDE + 8]);
  return t_masks[((size_t)((b*MH_N + h)*MW_N + w)) * T_N + u];
}

// ---- kernel 3: flat float4 grid-stride writer -----------------------------
__global__ __launch_bounds__(256) void k_write(
    const float* __restrict__ cls_logits, const float* __restrict__ pred_boxes,
    const float* __restrict__ mask_embs,  const float* __restrict__ protos,
    const float* __restrict__ t_masks,    const float* __restrict__ params,
    float* __restrict__ out) {
  const unsigned total_chunks = (unsigned)NROWS * ROW_N / 4u;   // 35,124,600
  unsigned idx    = blockIdx.x * 256u + threadIdx.x;
  unsigned stride = gridDim.x * 256u;
  for (unsigned c = idx; c < total_chunks; c += stride) {
    unsigned e0  = c * 4u;
    unsigned row = e0 / (unsigned)ROW_N;          // magic-mul division
    unsigned pos0 = e0 - row * (unsigned)ROW_N;
    float4 o;
    if (pos0 + 3u < (unsigned)ROW_N) {            // whole chunk in one row
      int b = row >= (unsigned)A_TOT;
      const float* pp = params + (size_t)row * PARAM_STRIDE;
      float4 P0 = *(const float4*)pp;
      float4 P1 = *(const float4*)(pp + 4);
      bool pure_seg = (pos0 >= 169u && pos0 + 3u < 4265u) || (pos0 >= 4267u);
      if (P1.x <= 0.5f && pure_seg) {
        o = make_float4(0.f, 0.f, 0.f, 0.f);
      } else {
        o.x = val_at(pos0,    row, b, cls_logits, pred_boxes, mask_embs, protos, t_masks, params, P0, P1);
        o.y = val_at(pos0+1u, row, b, cls_logits, pred_boxes, mask_embs, protos, t_masks, params, P0, P1);
        o.z = val_at(pos0+2u, row, b, cls_logits, pred_boxes, mask_embs, protos, t_masks, params, P0, P1);
        o.w = val_at(pos0+3u, row, b, cls_logits, pred_boxes, mask_embs, protos, t_masks, params, P0, P1);
      }
    } else {                                      // chunk straddles a row edge
      float tmp[4];
      #pragma unroll
      for (int j = 0; j < 4; j++) {
        unsigned pos = pos0 + j, r = row;
        if (pos >= (unsigned)ROW_N) { pos -= (unsigned)ROW_N; r = row + 1u; }
        int b = r >= (unsigned)A_TOT;
        const float* pp = params + (size_t)r * PARAM_STRIDE;
        float4 P0 = *(const float4*)pp;
        float4 P1 = *(const float4*)(pp + 4);
        tmp[j] = val_at(pos, r, b, cls_logits, pred_boxes, mask_embs, protos, t_masks, params, P0, P1);
      }
      o = make_float4(tmp[0], tmp[1], tmp[2], tmp[3]);
    }
    *(float4*)(out + (size_t)e0) = o;
  }
}

extern "C" void kernel_launch(void* const* d_in, const int* in_sizes, int n_in,
                              void* d_out, int out_size, void* d_ws, size_t ws_size,
                              hipStream_t stream) {
  const float* cls_logits   = (const float*)d_in[0];
  const float* pred_boxes   = (const float*)d_in[1];
  const float* mask_embs    = (const float*)d_in[2];
  const float* protos       = (const float*)d_in[3];
  const int*   target_cls   = (const int*)  d_in[4];
  const float* target_bbox  = (const float*)d_in[5];
  const float* target_masks = (const float*)d_in[6];
  const float* anchors      = (const float*)d_in[7];
  const float* scalers      = (const float*)d_in[8];
  float* out = (float*)d_out;

  float* ws     = (float*)d_ws;
  float* kth    = ws;                              // 200
  float* maxt   = kth    + B_N*T_N;                // 200
  float* maxiou = maxt   + B_N*T_N;                // 200
  float* params = ws + 600;                        // 16800*12 floats (16B-aligned)

  k_topk<<<B_N*T_N, 256, 0, stream>>>(cls_logits, pred_boxes, target_bbox,
                                      target_cls, anchors, kth, maxt, maxiou);
  dim3 gAsn((A_TOT + 255)/256, B_N);
  k_assign<<<gAsn, 256, 0, stream>>>(cls_logits, pred_boxes, target_bbox, target_cls,
                                     anchors, scalers, kth, maxt, maxiou, params);
  k_write<<<2048, 256, 0, stream>>>(cls_logits, pred_boxes, mask_embs, protos,
                                    target_masks, params, out);
}

// Round 5
// 236.070 us; speedup vs baseline: 1.2082x; 1.2082x over previous
//
#include <hip/hip_runtime.h>
#include <math.h>

#define A_TOT 8400
#define B_N   2
#define T_N   100
#define C_N   80
#define E_N   32
#define MH_N  64
#define MW_N  64
#define ROW_N 8363          // 4 + 80 + 85 + 4096 + 4098
#define NROWS (B_N*A_TOT)   // 16800
#define EPSF  1e-9f
#define PARAM_STRIDE 12

__device__ __forceinline__ float2 tmat_eval(
    float gx1, float gy1, float gx2, float gy2,
    float ax,  float ay,
    float px1, float py1, float px2, float py2,
    float cl) {
  float ix1 = fmaxf(gx1,px1), iy1 = fmaxf(gy1,py1);
  float ix2 = fminf(gx2,px2), iy2 = fminf(gy2,py2);
  float inter = fmaxf(ix2-ix1,0.f) * fmaxf(iy2-iy1,0.f);
  float wg = gx2-gx1, hg = gy2-gy1, wp = px2-px1, hp = py2-py1;
  float uni = wg*hg + wp*hp - inter + EPSF;
  float iou = inter / uni;
  float cw = fmaxf(gx2,px2) - fminf(gx1,px1);
  float ch = fmaxf(gy2,py2) - fminf(gy1,py1);
  float c2 = cw*cw + ch*ch + EPSF;
  float dx = gx1+gx2-px1-px2, dy = gy1+gy2-py1-py2;
  float rho2 = (dx*dx + dy*dy) * 0.25f;
  float da = atanf(wg/(hg+EPSF)) - atanf(wp/(hp+EPSF));
  float v  = 0.4052847345693511f * da * da;     // 4/pi^2
  float alpha = v / (1.f - iou + v + EPSF);
  float ciou = iou - rho2/c2 - alpha*v;
  float iouc = fminf(fmaxf(ciou, 0.f), 1.f);

  float tm = 0.f;
  if (ax > gx1 && ay > gy1 && ax < gx2 && ay < gy2) {   // strict grid mask
    float cp = 1.f / (1.f + expf(-cl));
    float i2 = iouc * iouc;
    tm = i2*i2*i2 * sqrtf(cp);                 // iou^6 * cls^0.5
  }
  return make_float2(tm, iouc);
}

// ---- kernel 0: materialize tmat + clipped iou, full occupancy -------------
__global__ __launch_bounds__(256) void k_tmat(
    const float* __restrict__ cls_logits, const float* __restrict__ pred_boxes,
    const float* __restrict__ target_bbox, const int* __restrict__ target_cls,
    const float* __restrict__ anchors,
    float* __restrict__ tmat, float* __restrict__ iouw) {
  int a  = blockIdx.x * 256 + threadIdx.x;
  int bt = blockIdx.y;
  if (a >= A_TOT) return;
  int b = bt / T_N;
  float4 g = *(const float4*)(target_bbox + bt*4);
  int   tc = target_cls[bt];
  float ax = anchors[a*2+0], ay = anchors[a*2+1];
  float4 pb = *(const float4*)(pred_boxes + ((size_t)(b*A_TOT+a))*4);
  float cl = cls_logits[((size_t)(b*A_TOT+a))*C_N + tc];
  float2 r = tmat_eval(g.x,g.y,g.z,g.w, ax,ay, pb.x,pb.y,pb.z,pb.w, cl);
  size_t o = (size_t)bt * A_TOT + a;
  tmat[o] = r.x;
  iouw[o] = r.y;
}

// ---- kernel 1: per (b,t): kth via nonzero compaction + 10-pass extract ----
__global__ __launch_bounds__(256) void k_topk(
    const float* __restrict__ tmat, const float* __restrict__ iouw,
    float* __restrict__ kth, float* __restrict__ maxt, float* __restrict__ maxiou) {
  int bt  = blockIdx.x;
  int tid = threadIdx.x;
  const float* row  = tmat + (size_t)bt * A_TOT;
  const float* irow = iouw + (size_t)bt * A_TOT;
  __shared__ float comp[A_TOT];
  __shared__ float red[256];
  __shared__ int   cnt, sidx;
  if (tid == 0) cnt = 0;
  __syncthreads();

  float lm = 0.f, li = 0.f;                    // values are >= 0
  for (int a = tid; a < A_TOT; a += 256) {
    float v = row[a];
    li = fmaxf(li, irow[a]);
    if (v > 0.f) { lm = fmaxf(lm, v); comp[atomicAdd(&cnt, 1)] = v; }
  }
  red[tid] = lm; __syncthreads();
  for (int s = 128; s > 0; s >>= 1) { if (tid < s) red[tid] = fmaxf(red[tid], red[tid+s]); __syncthreads(); }
  if (tid == 0) maxt[bt] = red[0];
  __syncthreads();
  red[tid] = li; __syncthreads();
  for (int s = 128; s > 0; s >>= 1) { if (tid < s) red[tid] = fmaxf(red[tid], red[tid+s]); __syncthreads(); }
  if (tid == 0) maxiou[bt] = red[0];
  __syncthreads();
  int count = cnt;

  float cur = -1e30f;
  for (int k = 0; k < 10; k++) {
    float l = -1e30f;
    for (int i = tid; i < count; i += 256) l = fmaxf(l, comp[i]);
    red[tid] = l; __syncthreads();
    for (int s = 128; s > 0; s >>= 1) { if (tid < s) red[tid] = fmaxf(red[tid], red[tid+s]); __syncthreads(); }
    float m = red[0];
    if (tid == 0) sidx = 0x7fffffff;
    __syncthreads();
    if (m > -1e30f) {
      for (int i = tid; i < count; i += 256) if (comp[i] == m) atomicMin(&sidx, i);
    }
    __syncthreads();
    if (tid == 0 && sidx != 0x7fffffff) comp[sidx] = -1e30f;  // remove ONE instance
    cur = m;
    __syncthreads();
  }
  if (tid == 0) kth[bt] = fmaxf(cur, 0.f);   // <10 positives -> kth = 0 (ref zero-pad)
}

// ---- kernel 2: per (b,a): assignment from stored tmat (bitwise-consistent)
__global__ __launch_bounds__(64) void k_assign(
    const float* __restrict__ tmat,
    const float* __restrict__ kth, const float* __restrict__ maxt, const float* __restrict__ maxiou,
    const float* __restrict__ target_bbox, const int* __restrict__ target_cls,
    const float* __restrict__ scalers,
    float* __restrict__ params) {
  int b   = blockIdx.y;
  int tid = threadIdx.x;
  int a   = blockIdx.x * 64 + tid;
  __shared__ float kths[T_N];
  for (int i = tid; i < T_N; i += 64) kths[i] = kth[b*T_N + i];
  __syncthreads();
  if (a >= A_TOT) return;

  const float* col = tmat + (size_t)b * T_N * A_TOT + a;
  float best = 0.f; int u = 0, any = 0;
  #pragma unroll 4
  for (int t = 0; t < T_N; t++) {
    float v = col[(size_t)t * A_TOT];
    if (v > 0.f && v >= kths[t]) {            // topk membership
      any = 1;
      if (v > best) { best = v; u = t; }      // argmax, first occurrence
    }
  }
  int bu = b*T_N + u;
  float ng = any ? best / (maxt[bu] + EPSF) * maxiou[bu] : 0.f;
  float4 tb = *(const float4*)(target_bbox + bu*4);
  float s = scalers[a];
  float area = (tb.z - tb.x) * (tb.w - tb.y) / (640.f*640.f);

  int row = b*A_TOT + a;
  float* pp = params + (size_t)row * PARAM_STRIDE;
  *(float4*)pp       = tb;
  *(float4*)(pp + 4) = make_float4(any ? 1.f : 0.f, ng, s, area);
  *(float4*)(pp + 8) = make_float4(__int_as_float(u), __int_as_float(target_cls[bu]), 0.f, 0.f);
}

// ---- value of output element `pos` within row `row` -----------------------
__device__ __forceinline__ float val_at(
    unsigned pos, unsigned row, int b,
    const float* __restrict__ cls_logits, const float* __restrict__ pred_boxes,
    const float* __restrict__ mask_embs,  const float* __restrict__ protos,
    const float* __restrict__ t_masks,    const float* __restrict__ params,
    float4 P0, float4 P1) {
  if (pos < 84u) {
    if (pos < 4u) return pred_boxes[(size_t)row*4 + pos] / P1.z;
    return cls_logits[(size_t)row*C_N + (pos-4u)];
  }
  if (pos < 169u) {
    if (pos < 88u) {
      float t = (pos==84u)?P0.x:((pos==85u)?P0.y:((pos==86u)?P0.z:P0.w));
      return t / P1.z;
    }
    if (pos == 88u) return P1.x;
    int c = (int)pos - 89;
    int ct = __float_as_int(params[(size_t)row*PARAM_STRIDE + 9]);
    return (P1.x > 0.5f && c == ct) ? P1.y : 0.f;
  }
  if (pos < 4265u) {                               // seg_pred
    if (P1.x <= 0.5f) return 0.f;
    unsigned p = pos - 169u; int h = p >> 6, w = p & 63;
    float fh = (float)h, fw = (float)w;
    float x1s = P0.x*0.1f, y1s = P0.y*0.1f, x2s = P0.z*0.1f, y2s = P0.w*0.1f;
    if (!(fh >= y1s && fh < y2s && fw >= x1s && fw < x2s)) return 0.f;
    const float* pr = protos   + ((size_t)((b*MH_N + h)*MW_N + w)) * E_N;
    const float* se = mask_embs + (size_t)row * E_N;
    float acc = 0.f;
    #pragma unroll
    for (int e = 0; e < E_N; e++) acc += se[e] * pr[e];
    return 1.f / (1.f + expf(-acc));
  }
  if (pos == 4265u) return P1.w;
  if (pos == 4266u) return P1.x;
  // align_seg
  if (P1.x <= 0.5f) return 0.f;
  unsigned p = pos - 4267u; int h = p >> 6, w = p & 63;
  float fh = (float)h, fw = (float)w;
  float x1s = P0.x*0.1f, y1s = P0.y*0.1f, x2s = P0.z*0.1f, y2s = P0.w*0.1f;
  if (!(fh >= y1s && fh < y2s && fw >= x1s && fw < x2s)) return 0.f;
  int u = __float_as_int(params[(size_t)row*PARAM_STRIDE + 8]);
  return t_masks[((size_t)((b*MH_N + h)*MW_N + w)) * T_N + u];
}

// ---- kernel 3: flat float4 grid-stride writer (unchanged from round 4) ----
__global__ __launch_bounds__(256) void k_write(
    const float* __restrict__ cls_logits, const float* __restrict__ pred_boxes,
    const float* __restrict__ mask_embs,  const float* __restrict__ protos,
    const float* __restrict__ t_masks,    const float* __restrict__ params,
    float* __restrict__ out) {
  const unsigned total_chunks = (unsigned)NROWS * ROW_N / 4u;   // 35,124,600
  unsigned idx    = blockIdx.x * 256u + threadIdx.x;
  unsigned stride = gridDim.x * 256u;
  for (unsigned c = idx; c < total_chunks; c += stride) {
    unsigned e0  = c * 4u;
    unsigned row = e0 / (unsigned)ROW_N;
    unsigned pos0 = e0 - row * (unsigned)ROW_N;
    float4 o;
    if (pos0 + 3u < (unsigned)ROW_N) {            // whole chunk in one row
      int b = row >= (unsigned)A_TOT;
      const float* pp = params + (size_t)row * PARAM_STRIDE;
      float4 P0 = *(const float4*)pp;
      float4 P1 = *(const float4*)(pp + 4);
      bool pure_seg = (pos0 >= 169u && pos0 + 3u < 4265u) || (pos0 >= 4267u);
      if (P1.x <= 0.5f && pure_seg) {
        o = make_float4(0.f, 0.f, 0.f, 0.f);
      } else {
        o.x = val_at(pos0,    row, b, cls_logits, pred_boxes, mask_embs, protos, t_masks, params, P0, P1);
        o.y = val_at(pos0+1u, row, b, cls_logits, pred_boxes, mask_embs, protos, t_masks, params, P0, P1);
        o.z = val_at(pos0+2u, row, b, cls_logits, pred_boxes, mask_embs, protos, t_masks, params, P0, P1);
        o.w = val_at(pos0+3u, row, b, cls_logits, pred_boxes, mask_embs, protos, t_masks, params, P0, P1);
      }
    } else {                                      // chunk straddles a row edge
      float tmp[4];
      #pragma unroll
      for (int j = 0; j < 4; j++) {
        unsigned pos = pos0 + j, r = row;
        if (pos >= (unsigned)ROW_N) { pos -= (unsigned)ROW_N; r = row + 1u; }
        int b = r >= (unsigned)A_TOT;
        const float* pp = params + (size_t)r * PARAM_STRIDE;
        float4 P0 = *(const float4*)pp;
        float4 P1 = *(const float4*)(pp + 4);
        tmp[j] = val_at(pos, r, b, cls_logits, pred_boxes, mask_embs, protos, t_masks, params, P0, P1);
      }
      o = make_float4(tmp[0], tmp[1], tmp[2], tmp[3]);
    }
    *(float4*)(out + (size_t)e0) = o;
  }
}

extern "C" void kernel_launch(void* const* d_in, const int* in_sizes, int n_in,
                              void* d_out, int out_size, void* d_ws, size_t ws_size,
                              hipStream_t stream) {
  const float* cls_logits   = (const float*)d_in[0];
  const float* pred_boxes   = (const float*)d_in[1];
  const float* mask_embs    = (const float*)d_in[2];
  const float* protos       = (const float*)d_in[3];
  const int*   target_cls   = (const int*)  d_in[4];
  const float* target_bbox  = (const float*)d_in[5];
  const float* target_masks = (const float*)d_in[6];
  const float* anchors      = (const float*)d_in[7];
  const float* scalers      = (const float*)d_in[8];
  float* out = (float*)d_out;

  // ws layout (floats); ~14.2 MB total, ws_size ~2.2 GB
  float* ws     = (float*)d_ws;
  float* kth    = ws;                               // 200
  float* maxt   = kth    + B_N*T_N;                 // 200
  float* maxiou = maxt   + B_N*T_N;                 // 200
  float* params = ws + 600;                         // 16800*12
  float* tmat   = params + (size_t)NROWS*PARAM_STRIDE;   // 1,680,000
  float* iouw   = tmat + (size_t)B_N*T_N*A_TOT;          // 1,680,000

  dim3 gT((A_TOT + 255)/256, B_N*T_N);              // 33 x 200
  k_tmat<<<gT, 256, 0, stream>>>(cls_logits, pred_boxes, target_bbox, target_cls,
                                 anchors, tmat, iouw);
  k_topk<<<B_N*T_N, 256, 0, stream>>>(tmat, iouw, kth, maxt, maxiou);
  dim3 gAsn((A_TOT + 63)/64, B_N);                  // 132 x 2
  k_assign<<<gAsn, 64, 0, stream>>>(tmat, kth, maxt, maxiou, target_bbox,
                                    target_cls, scalers, params);
  k_write<<<2048, 256, 0, stream>>>(cls_logits, pred_boxes, mask_embs, protos,
                                    target_masks, params, out);
}

// Round 7
// 187.588 us; speedup vs baseline: 1.5204x; 1.2584x over previous
//
#include <hip/hip_runtime.h>
#include <math.h>

#define A_TOT 8400
#define B_N   2
#define T_N   100
#define C_N   80
#define E_N   32
#define MH_N  64
#define MW_N  64
#define ROW_N 8363          // 4 + 80 + 85 + 4096 + 4098
#define NROWS (B_N*A_TOT)   // 16800
#define EPSF  1e-9f
#define PARAM_STRIDE 12
#define COMP_CAP 1536       // max positives per target row is <=1189 (grid mask)

typedef float vfloat4 __attribute__((ext_vector_type(4)));

__device__ __forceinline__ float2 tmat_eval(
    float gx1, float gy1, float gx2, float gy2,
    float ax,  float ay,
    float px1, float py1, float px2, float py2,
    float cl) {
  float ix1 = fmaxf(gx1,px1), iy1 = fmaxf(gy1,py1);
  float ix2 = fminf(gx2,px2), iy2 = fminf(gy2,py2);
  float inter = fmaxf(ix2-ix1,0.f) * fmaxf(iy2-iy1,0.f);
  float wg = gx2-gx1, hg = gy2-gy1, wp = px2-px1, hp = py2-py1;
  float uni = wg*hg + wp*hp - inter + EPSF;
  float iou = inter / uni;
  float cw = fmaxf(gx2,px2) - fminf(gx1,px1);
  float ch = fmaxf(gy2,py2) - fminf(gy1,py1);
  float c2 = cw*cw + ch*ch + EPSF;
  float dx = gx1+gx2-px1-px2, dy = gy1+gy2-py1-py2;
  float rho2 = (dx*dx + dy*dy) * 0.25f;
  float da = atanf(wg/(hg+EPSF)) - atanf(wp/(hp+EPSF));
  float v  = 0.4052847345693511f * da * da;     // 4/pi^2
  float alpha = v / (1.f - iou + v + EPSF);
  float ciou = iou - rho2/c2 - alpha*v;
  float iouc = fminf(fmaxf(ciou, 0.f), 1.f);

  float tm = 0.f;
  if (ax > gx1 && ay > gy1 && ax < gx2 && ay < gy2) {   // strict grid mask
    float cp = 1.f / (1.f + expf(-cl));
    float i2 = iouc * iouc;
    tm = i2*i2*i2 * sqrtf(cp);                 // iou^6 * cls^0.5
  }
  return make_float2(tm, iouc);
}

// ---- kernel 1: per (b,t): compute row, store tmat, kth/maxt/maxiou --------
__global__ __launch_bounds__(256) void k_score(
    const float* __restrict__ cls_logits, const float* __restrict__ pred_boxes,
    const float* __restrict__ target_bbox, const int* __restrict__ target_cls,
    const float* __restrict__ anchors,
    float* __restrict__ tmat,
    float* __restrict__ kth, float* __restrict__ maxt, float* __restrict__ maxiou) {
  int bt  = blockIdx.x;
  int b   = bt / T_N;
  int tid = threadIdx.x;
  __shared__ float comp[COMP_CAP];
  __shared__ float red[256];
  __shared__ int   cnt, sidx;
  if (tid == 0) cnt = 0;
  __syncthreads();

  float4 g = *(const float4*)(target_bbox + bt*4);
  int   tc = target_cls[bt];
  float* trow = tmat + (size_t)bt * A_TOT;

  float lm = 0.f, li = 0.f;                    // values are >= 0
  for (int a = tid; a < A_TOT; a += 256) {
    float ax = anchors[a*2+0], ay = anchors[a*2+1];
    float4 pb = *(const float4*)(pred_boxes + ((size_t)(b*A_TOT+a))*4);
    float cl = cls_logits[((size_t)(b*A_TOT+a))*C_N + tc];
    float2 r = tmat_eval(g.x,g.y,g.z,g.w, ax,ay, pb.x,pb.y,pb.z,pb.w, cl);
    trow[a] = r.x;
    li = fmaxf(li, r.y);
    if (r.x > 0.f) {
      lm = fmaxf(lm, r.x);
      int i = atomicAdd(&cnt, 1);
      if (i < COMP_CAP) comp[i] = r.x;
    }
  }
  red[tid] = lm; __syncthreads();
  for (int s = 128; s > 0; s >>= 1) { if (tid < s) red[tid] = fmaxf(red[tid], red[tid+s]); __syncthreads(); }
  if (tid == 0) maxt[bt] = red[0];
  __syncthreads();
  red[tid] = li; __syncthreads();
  for (int s = 128; s > 0; s >>= 1) { if (tid < s) red[tid] = fmaxf(red[tid], red[tid+s]); __syncthreads(); }
  if (tid == 0) maxiou[bt] = red[0];
  __syncthreads();
  int count = min(cnt, COMP_CAP);

  float cur = -1e30f;
  for (int k = 0; k < 10; k++) {
    float l = -1e30f;
    for (int i = tid; i < count; i += 256) l = fmaxf(l, comp[i]);
    red[tid] = l; __syncthreads();
    for (int s = 128; s > 0; s >>= 1) { if (tid < s) red[tid] = fmaxf(red[tid], red[tid+s]); __syncthreads(); }
    float m = red[0];
    if (tid == 0) sidx = 0x7fffffff;
    __syncthreads();
    if (m > -1e30f) {
      for (int i = tid; i < count; i += 256) if (comp[i] == m) atomicMin(&sidx, i);
    }
    __syncthreads();
    if (tid == 0 && sidx != 0x7fffffff) comp[sidx] = -1e30f;  // remove ONE instance
    cur = m;
    __syncthreads();
  }
  if (tid == 0) kth[bt] = fmaxf(cur, 0.f);   // <10 positives -> kth=0 (ref zero-pad)
}

// ---- kernel 2: per (b,a): assignment from stored tmat (bitwise-consistent)
__global__ __launch_bounds__(64) void k_assign(
    const float* __restrict__ tmat,
    const float* __restrict__ kth, const float* __restrict__ maxt, const float* __restrict__ maxiou,
    const float* __restrict__ target_bbox, const int* __restrict__ target_cls,
    const float* __restrict__ scalers,
    float* __restrict__ params) {
  int b   = blockIdx.y;
  int tid = threadIdx.x;
  int a   = blockIdx.x * 64 + tid;
  __shared__ float kths[T_N];
  for (int i = tid; i < T_N; i += 64) kths[i] = kth[b*T_N + i];
  __syncthreads();
  if (a >= A_TOT) return;

  const float* col = tmat + (size_t)b * T_N * A_TOT + a;
  float best = 0.f; int u = 0, any = 0;
  #pragma unroll 4
  for (int t = 0; t < T_N; t++) {
    float v = col[(size_t)t * A_TOT];
    if (v > 0.f && v >= kths[t]) {            // topk membership
      any = 1;
      if (v > best) { best = v; u = t; }      // argmax, first occurrence
    }
  }
  int bu = b*T_N + u;
  float ng = any ? best / (maxt[bu] + EPSF) * maxiou[bu] : 0.f;
  float4 tb = *(const float4*)(target_bbox + bu*4);
  float s = scalers[a];
  float area = (tb.z - tb.x) * (tb.w - tb.y) / (640.f*640.f);

  int row = b*A_TOT + a;
  float* pp = params + (size_t)row * PARAM_STRIDE;
  *(float4*)pp       = tb;
  *(float4*)(pp + 4) = make_float4(any ? 1.f : 0.f, ng, s, area);
  *(float4*)(pp + 8) = make_float4(__int_as_float(u), __int_as_float(target_cls[bu]), 0.f, 0.f);
}

// ---- value of output element `pos` within row `row` -----------------------
__device__ __forceinline__ float val_at(
    unsigned pos, unsigned row, int b,
    const float* __restrict__ cls_logits, const float* __restrict__ pred_boxes,
    const float* __restrict__ mask_embs,  const float* __restrict__ protos,
    const float* __restrict__ t_masks,    const float* __restrict__ params,
    float4 P0, float4 P1) {
  if (pos < 84u) {
    if (pos < 4u) return pred_boxes[(size_t)row*4 + pos] / P1.z;
    return cls_logits[(size_t)row*C_N + (pos-4u)];
  }
  if (pos < 169u) {
    if (pos < 88u) {
      float t = (pos==84u)?P0.x:((pos==85u)?P0.y:((pos==86u)?P0.z:P0.w));
      return t / P1.z;
    }
    if (pos == 88u) return P1.x;
    int c = (int)pos - 89;
    int ct = __float_as_int(params[(size_t)row*PARAM_STRIDE + 9]);
    return (P1.x > 0.5f && c == ct) ? P1.y : 0.f;
  }
  if (pos < 4265u) {                               // seg_pred
    if (P1.x <= 0.5f) return 0.f;
    unsigned p = pos - 169u; int h = p >> 6, w = p & 63;
    float fh = (float)h, fw = (float)w;
    float x1s = P0.x*0.1f, y1s = P0.y*0.1f, x2s = P0.z*0.1f, y2s = P0.w*0.1f;
    if (!(fh >= y1s && fh < y2s && fw >= x1s && fw < x2s)) return 0.f;
    const float* pr = protos   + ((size_t)((b*MH_N + h)*MW_N + w)) * E_N;
    const float* se = mask_embs + (size_t)row * E_N;
    float acc = 0.f;
    #pragma unroll
    for (int e = 0; e < E_N; e++) acc += se[e] * pr[e];
    return 1.f / (1.f + expf(-acc));
  }
  if (pos == 4265u) return P1.w;
  if (pos == 4266u) return P1.x;
  // align_seg
  if (P1.x <= 0.5f) return 0.f;
  unsigned p = pos - 4267u; int h = p >> 6, w = p & 63;
  float fh = (float)h, fw = (float)w;
  float x1s = P0.x*0.1f, y1s = P0.y*0.1f, x2s = P0.z*0.1f, y2s = P0.w*0.1f;
  if (!(fh >= y1s && fh < y2s && fw >= x1s && fw < x2s)) return 0.f;
  int u = __float_as_int(params[(size_t)row*PARAM_STRIDE + 8]);
  return t_masks[((size_t)((b*MH_N + h)*MW_N + w)) * T_N + u];
}

// ---- kernel 3: flat float4 grid-stride writer, nontemporal stores ---------
__global__ __launch_bounds__(256) void k_write(
    const float* __restrict__ cls_logits, const float* __restrict__ pred_boxes,
    const float* __restrict__ mask_embs,  const float* __restrict__ protos,
    const float* __restrict__ t_masks,    const float* __restrict__ params,
    float* __restrict__ out) {
  const unsigned total_chunks = (unsigned)NROWS * ROW_N / 4u;   // 35,124,600
  unsigned idx    = blockIdx.x * 256u + threadIdx.x;
  unsigned stride = gridDim.x * 256u;
  for (unsigned c = idx; c < total_chunks; c += stride) {
    unsigned e0  = c * 4u;
    unsigned row = e0 / (unsigned)ROW_N;
    unsigned pos0 = e0 - row * (unsigned)ROW_N;
    vfloat4 o;
    if (pos0 + 3u < (unsigned)ROW_N) {            // whole chunk in one row
      int b = row >= (unsigned)A_TOT;
      const float* pp = params + (size_t)row * PARAM_STRIDE;
      float4 P0 = *(const float4*)pp;
      float4 P1 = *(const float4*)(pp + 4);
      bool pure_seg = (pos0 >= 169u && pos0 + 3u < 4265u) || (pos0 >= 4267u);
      if (P1.x <= 0.5f && pure_seg) {
        o = (vfloat4)(0.f);
      } else {
        o.x = val_at(pos0,    row, b, cls_logits, pred_boxes, mask_embs, protos, t_masks, params, P0, P1);
        o.y = val_at(pos0+1u, row, b, cls_logits, pred_boxes, mask_embs, protos, t_masks, params, P0, P1);
        o.z = val_at(pos0+2u, row, b, cls_logits, pred_boxes, mask_embs, protos, t_masks, params, P0, P1);
        o.w = val_at(pos0+3u, row, b, cls_logits, pred_boxes, mask_embs, protos, t_masks, params, P0, P1);
      }
    } else {                                      // chunk straddles a row edge
      float tmp[4];
      #pragma unroll
      for (int j = 0; j < 4; j++) {
        unsigned pos = pos0 + j, r = row;
        if (pos >= (unsigned)ROW_N) { pos -= (unsigned)ROW_N; r = row + 1u; }
        int b = r >= (unsigned)A_TOT;
        const float* pp = params + (size_t)r * PARAM_STRIDE;
        float4 P0 = *(const float4*)pp;
        float4 P1 = *(const float4*)(pp + 4);
        tmp[j] = val_at(pos, r, b, cls_logits, pred_boxes, mask_embs, protos, t_masks, params, P0, P1);
      }
      o.x = tmp[0]; o.y = tmp[1]; o.z = tmp[2]; o.w = tmp[3];
    }
    __builtin_nontemporal_store(o, (vfloat4*)(out + (size_t)e0));
  }
}

extern "C" void kernel_launch(void* const* d_in, const int* in_sizes, int n_in,
                              void* d_out, int out_size, void* d_ws, size_t ws_size,
                              hipStream_t stream) {
  const float* cls_logits   = (const float*)d_in[0];
  const float* pred_boxes   = (const float*)d_in[1];
  const float* mask_embs    = (const float*)d_in[2];
  const float* protos       = (const float*)d_in[3];
  const int*   target_cls   = (const int*)  d_in[4];
  const float* target_bbox  = (const float*)d_in[5];
  const float* target_masks = (const float*)d_in[6];
  const float* anchors      = (const float*)d_in[7];
  const float* scalers      = (const float*)d_in[8];
  float* out = (float*)d_out;

  // ws layout (floats); ~7.5 MB total
  float* ws     = (float*)d_ws;
  float* kth    = ws;                               // 200
  float* maxt   = kth    + B_N*T_N;                 // 200
  float* maxiou = maxt   + B_N*T_N;                 // 200
  float* params = ws + 600;                         // 16800*12
  float* tmat   = params + (size_t)NROWS*PARAM_STRIDE;   // 1,680,000

  k_score<<<B_N*T_N, 256, 0, stream>>>(cls_logits, pred_boxes, target_bbox,
                                       target_cls, anchors, tmat, kth, maxt, maxiou);
  dim3 gAsn((A_TOT + 63)/64, B_N);                  // 132 x 2
  k_assign<<<gAsn, 64, 0, stream>>>(tmat, kth, maxt, maxiou, target_bbox,
                                    target_cls, scalers, params);
  k_write<<<2048, 256, 0, stream>>>(cls_logits, pred_boxes, mask_embs, protos,
                                    target_masks, params, out);
}

// Round 8
// 182.469 us; speedup vs baseline: 1.5631x; 1.0281x over previous
//
#include <hip/hip_runtime.h>
#include <math.h>

#define A_TOT 8400
#define B_N   2
#define T_N   100
#define C_N   80
#define E_N   32
#define MH_N  64
#define MW_N  64
#define ROW_N 8363          // 4 + 80 + 85 + 4096 + 4098
#define NROWS (B_N*A_TOT)   // 16800
#define EPSF  1e-9f
#define PARAM_STRIDE 12
#define COMP_CAP 1536       // max positives per target row <=1189 (grid mask)
#define NEGINF -1e30f

typedef float vfloat4 __attribute__((ext_vector_type(4)));

// ---- kernel 0: hoist atan terms (per-bt and per-(b,a)) --------------------
__global__ __launch_bounds__(256) void k_prep(
    const float* __restrict__ pred_boxes, const float* __restrict__ target_bbox,
    float* __restrict__ pred_atan, float* __restrict__ tgt_atan) {
  int i = blockIdx.x * 256 + threadIdx.x;
  if (i < NROWS) {
    float4 pb = *(const float4*)(pred_boxes + (size_t)i*4);
    pred_atan[i] = atanf((pb.z - pb.x) / ((pb.w - pb.y) + EPSF));
  }
  if (i < B_N*T_N) {
    float4 g = *(const float4*)(target_bbox + i*4);
    tgt_atan[i] = atanf((g.z - g.x) / ((g.w - g.y) + EPSF));
  }
}

__device__ __forceinline__ float2 tmat_eval(
    float gx1, float gy1, float gx2, float gy2,
    float ax,  float ay,
    float px1, float py1, float px2, float py2,
    float cl, float atg, float atp) {
  float ix1 = fmaxf(gx1,px1), iy1 = fmaxf(gy1,py1);
  float ix2 = fminf(gx2,px2), iy2 = fminf(gy2,py2);
  float inter = fmaxf(ix2-ix1,0.f) * fmaxf(iy2-iy1,0.f);
  float wg = gx2-gx1, hg = gy2-gy1, wp = px2-px1, hp = py2-py1;
  float uni = wg*hg + wp*hp - inter + EPSF;
  float iou = inter / uni;
  float cw = fmaxf(gx2,px2) - fminf(gx1,px1);
  float ch = fmaxf(gy2,py2) - fminf(gy1,py1);
  float c2 = cw*cw + ch*ch + EPSF;
  float dx = gx1+gx2-px1-px2, dy = gy1+gy2-py1-py2;
  float rho2 = (dx*dx + dy*dy) * 0.25f;
  float da = atg - atp;
  float v  = 0.4052847345693511f * da * da;     // 4/pi^2
  float alpha = v / (1.f - iou + v + EPSF);
  float ciou = iou - rho2/c2 - alpha*v;
  float iouc = fminf(fmaxf(ciou, 0.f), 1.f);

  float tm = 0.f;
  if (ax > gx1 && ay > gy1 && ax < gx2 && ay < gy2) {   // strict grid mask
    float cp = 1.f / (1.f + expf(-cl));
    float i2 = iouc * iouc;
    tm = i2*i2*i2 * sqrtf(cp);                 // iou^6 * cls^0.5
  }
  return make_float2(tm, iouc);
}

// ---- kernel 1: per (b,t): row CIoU -> tmat; kth/maxt/maxiou, few barriers -
__global__ __launch_bounds__(512) void k_score(
    const float* __restrict__ cls_logits, const float* __restrict__ pred_boxes,
    const float* __restrict__ target_bbox, const int* __restrict__ target_cls,
    const float* __restrict__ anchors,
    const float* __restrict__ pred_atan, const float* __restrict__ tgt_atan,
    float* __restrict__ tmat,
    float* __restrict__ kth, float* __restrict__ maxt, float* __restrict__ maxiou) {
  int bt   = blockIdx.x;
  int b    = bt / T_N;
  int tid  = threadIdx.x;
  int lane = tid & 63, wid = tid >> 6;
  __shared__ float comp[COMP_CAP];
  __shared__ float redm[8], redi[8];
  __shared__ float wtop[8][10];
  __shared__ int   cnt;
  if (tid == 0) cnt = 0;
  __syncthreads();

  float4 g  = *(const float4*)(target_bbox + bt*4);
  int    tc = target_cls[bt];
  float atg = tgt_atan[bt];
  float* trow = tmat + (size_t)bt * A_TOT;

  float lm = 0.f, li = 0.f;
  for (int a = tid; a < A_TOT; a += 512) {
    float ax = anchors[a*2+0], ay = anchors[a*2+1];
    float4 pb = *(const float4*)(pred_boxes + ((size_t)(b*A_TOT+a))*4);
    float cl = cls_logits[((size_t)(b*A_TOT+a))*C_N + tc];
    float2 r = tmat_eval(g.x,g.y,g.z,g.w, ax,ay, pb.x,pb.y,pb.z,pb.w,
                         cl, atg, pred_atan[b*A_TOT + a]);
    trow[a] = r.x;
    li = fmaxf(li, r.y);
    if (r.x > 0.f) {
      lm = fmaxf(lm, r.x);
      comp[atomicAdd(&cnt, 1)] = r.x;
    }
  }
  #pragma unroll
  for (int off = 32; off; off >>= 1) {
    lm = fmaxf(lm, __shfl_xor(lm, off));
    li = fmaxf(li, __shfl_xor(li, off));
  }
  if (lane == 0) { redm[wid] = lm; redi[wid] = li; }
  __syncthreads();
  if (tid == 0) {
    float m = redm[0], mi = redi[0];
    #pragma unroll
    for (int w = 1; w < 8; w++) { m = fmaxf(m, redm[w]); mi = fmaxf(mi, redi[w]); }
    maxt[bt] = m; maxiou[bt] = mi;
  }
  int count = cnt;   // safe: after __syncthreads

  // per-wave top-10 over its strided slice of comp (<=3 elems/lane, in regs)
  int base = wid*64 + lane;
  float e0 = (base        < count) ? comp[base]        : NEGINF;
  float e1 = (base + 512  < count) ? comp[base + 512]  : NEGINF;
  float e2 = (base + 1024 < count) ? comp[base + 1024] : NEGINF;
  float mytop = NEGINF;
  #pragma unroll
  for (int k = 0; k < 10; k++) {
    float bv = e0; int bs = 0;
    if (e1 > bv) { bv = e1; bs = 1; }
    if (e2 > bv) { bv = e2; bs = 2; }
    float v = bv; int id = (lane << 2) | bs;
    #pragma unroll
    for (int off = 32; off; off >>= 1) {
      float ov = __shfl_xor(v, off); int oid = __shfl_xor(id, off);
      if (ov > v || (ov == v && oid < id)) { v = ov; id = oid; }
    }
    if ((id >> 2) == lane) {           // winner removes its element
      int s = id & 3;
      if (s == 0) e0 = NEGINF; else if (s == 1) e1 = NEGINF; else e2 = NEGINF;
    }
    if (lane == k) mytop = v;
  }
  if (lane < 10) wtop[wid][lane] = mytop;
  __syncthreads();

  if (wid == 0) {                      // merge 80 candidates in wave 0
    int ia = lane, ib = 64 + lane;
    float f0 = wtop[ia/10][ia%10];
    float f1 = (ib < 80) ? wtop[ib/10][ib%10] : NEGINF;
    float cur = NEGINF;
    #pragma unroll
    for (int k = 0; k < 10; k++) {
      float bv = f0; int bs = 0;
      if (f1 > bv) { bv = f1; bs = 1; }
      float v = bv; int id = (lane << 1) | bs;
      #pragma unroll
      for (int off = 32; off; off >>= 1) {
        float ov = __shfl_xor(v, off); int oid = __shfl_xor(id, off);
        if (ov > v || (ov == v && oid < id)) { v = ov; id = oid; }
      }
      if ((id >> 1) == lane) { if ((id & 1) == 0) f0 = NEGINF; else f1 = NEGINF; }
      cur = v;
    }
    if (lane == 0) kth[bt] = fmaxf(cur, 0.f);   // <10 positives -> 0 (ref zero-pad)
  }
}

// ---- kernel 2: per (b,a): assignment from stored tmat (bitwise-consistent)
__global__ __launch_bounds__(64) void k_assign(
    const float* __restrict__ tmat,
    const float* __restrict__ kth, const float* __restrict__ maxt, const float* __restrict__ maxiou,
    const float* __restrict__ target_bbox, const int* __restrict__ target_cls,
    const float* __restrict__ scalers,
    float* __restrict__ params) {
  int b   = blockIdx.y;
  int tid = threadIdx.x;
  int a   = blockIdx.x * 64 + tid;
  __shared__ float kths[T_N];
  for (int i = tid; i < T_N; i += 64) kths[i] = kth[b*T_N + i];
  __syncthreads();
  if (a >= A_TOT) return;

  const float* col = tmat + (size_t)b * T_N * A_TOT + a;
  float best = 0.f; int u = 0, any = 0;
  #pragma unroll 4
  for (int t = 0; t < T_N; t++) {
    float v = col[(size_t)t * A_TOT];
    if (v > 0.f && v >= kths[t]) {            // topk membership
      any = 1;
      if (v > best) { best = v; u = t; }      // argmax, first occurrence
    }
  }
  int bu = b*T_N + u;
  float ng = any ? best / (maxt[bu] + EPSF) * maxiou[bu] : 0.f;
  float4 tb = *(const float4*)(target_bbox + bu*4);
  float s = scalers[a];
  float area = (tb.z - tb.x) * (tb.w - tb.y) / (640.f*640.f);

  int row = b*A_TOT + a;
  float* pp = params + (size_t)row * PARAM_STRIDE;
  *(float4*)pp       = tb;
  *(float4*)(pp + 4) = make_float4(any ? 1.f : 0.f, ng, s, area);
  *(float4*)(pp + 8) = make_float4(__int_as_float(u), __int_as_float(target_cls[bu]), 0.f, 0.f);
}

// ---- value of output element `pos` within row `row` -----------------------
__device__ __forceinline__ float val_at(
    unsigned pos, unsigned row, int b,
    const float* __restrict__ cls_logits, const float* __restrict__ pred_boxes,
    const float* __restrict__ mask_embs,  const float* __restrict__ protos,
    const float* __restrict__ t_masks,    const float* __restrict__ params,
    float4 P0, float4 P1) {
  if (pos < 84u) {
    if (pos < 4u) return pred_boxes[(size_t)row*4 + pos] / P1.z;
    return cls_logits[(size_t)row*C_N + (pos-4u)];
  }
  if (pos < 169u) {
    if (pos < 88u) {
      float t = (pos==84u)?P0.x:((pos==85u)?P0.y:((pos==86u)?P0.z:P0.w));
      return t / P1.z;
    }
    if (pos == 88u) return P1.x;
    int c = (int)pos - 89;
    int ct = __float_as_int(params[(size_t)row*PARAM_STRIDE + 9]);
    return (P1.x > 0.5f && c == ct) ? P1.y : 0.f;
  }
  if (pos < 4265u) {                               // seg_pred
    if (P1.x <= 0.5f) return 0.f;
    unsigned p = pos - 169u; int h = p >> 6, w = p & 63;
    float fh = (float)h, fw = (float)w;
    float x1s = P0.x*0.1f, y1s = P0.y*0.1f, x2s = P0.z*0.1f, y2s = P0.w*0.1f;
    if (!(fh >= y1s && fh < y2s && fw >= x1s && fw < x2s)) return 0.f;
    const float* pr = protos   + ((size_t)((b*MH_N + h)*MW_N + w)) * E_N;
    const float* se = mask_embs + (size_t)row * E_N;
    float acc = 0.f;
    #pragma unroll
    for (int e = 0; e < E_N; e++) acc += se[e] * pr[e];
    return 1.f / (1.f + expf(-acc));
  }
  if (pos == 4265u) return P1.w;
  if (pos == 4266u) return P1.x;
  // align_seg
  if (P1.x <= 0.5f) return 0.f;
  unsigned p = pos - 4267u; int h = p >> 6, w = p & 63;
  float fh = (float)h, fw = (float)w;
  float x1s = P0.x*0.1f, y1s = P0.y*0.1f, x2s = P0.z*0.1f, y2s = P0.w*0.1f;
  if (!(fh >= y1s && fh < y2s && fw >= x1s && fw < x2s)) return 0.f;
  int u = __float_as_int(params[(size_t)row*PARAM_STRIDE + 8]);
  return t_masks[((size_t)((b*MH_N + h)*MW_N + w)) * T_N + u];
}

// ---- kernel 3: flat float4 grid-stride writer, NT stores (unchanged) ------
__global__ __launch_bounds__(256) void k_write(
    const float* __restrict__ cls_logits, const float* __restrict__ pred_boxes,
    const float* __restrict__ mask_embs,  const float* __restrict__ protos,
    const float* __restrict__ t_masks,    const float* __restrict__ params,
    float* __restrict__ out) {
  const unsigned total_chunks = (unsigned)NROWS * ROW_N / 4u;   // 35,124,600
  unsigned idx    = blockIdx.x * 256u + threadIdx.x;
  unsigned stride = gridDim.x * 256u;
  for (unsigned c = idx; c < total_chunks; c += stride) {
    unsigned e0  = c * 4u;
    unsigned row = e0 / (unsigned)ROW_N;
    unsigned pos0 = e0 - row * (unsigned)ROW_N;
    vfloat4 o;
    if (pos0 + 3u < (unsigned)ROW_N) {            // whole chunk in one row
      int b = row >= (unsigned)A_TOT;
      const float* pp = params + (size_t)row * PARAM_STRIDE;
      float4 P0 = *(const float4*)pp;
      float4 P1 = *(const float4*)(pp + 4);
      bool pure_seg = (pos0 >= 169u && pos0 + 3u < 4265u) || (pos0 >= 4267u);
      if (P1.x <= 0.5f && pure_seg) {
        o = (vfloat4)(0.f);
      } else {
        o.x = val_at(pos0,    row, b, cls_logits, pred_boxes, mask_embs, protos, t_masks, params, P0, P1);
        o.y = val_at(pos0+1u, row, b, cls_logits, pred_boxes, mask_embs, protos, t_masks, params, P0, P1);
        o.z = val_at(pos0+2u, row, b, cls_logits, pred_boxes, mask_embs, protos, t_masks, params, P0, P1);
        o.w = val_at(pos0+3u, row, b, cls_logits, pred_boxes, mask_embs, protos, t_masks, params, P0, P1);
      }
    } else {                                      // chunk straddles a row edge
      float tmp[4];
      #pragma unroll
      for (int j = 0; j < 4; j++) {
        unsigned pos = pos0 + j, r = row;
        if (pos >= (unsigned)ROW_N) { pos -= (unsigned)ROW_N; r = row + 1u; }
        int b = r >= (unsigned)A_TOT;
        const float* pp = params + (size_t)r * PARAM_STRIDE;
        float4 P0 = *(const float4*)pp;
        float4 P1 = *(const float4*)(pp + 4);
        tmp[j] = val_at(pos, r, b, cls_logits, pred_boxes, mask_embs, protos, t_masks, params, P0, P1);
      }
      o.x = tmp[0]; o.y = tmp[1]; o.z = tmp[2]; o.w = tmp[3];
    }
    __builtin_nontemporal_store(o, (vfloat4*)(out + (size_t)e0));
  }
}

extern "C" void kernel_launch(void* const* d_in, const int* in_sizes, int n_in,
                              void* d_out, int out_size, void* d_ws, size_t ws_size,
                              hipStream_t stream) {
  const float* cls_logits   = (const float*)d_in[0];
  const float* pred_boxes   = (const float*)d_in[1];
  const float* mask_embs    = (const float*)d_in[2];
  const float* protos       = (const float*)d_in[3];
  const int*   target_cls   = (const int*)  d_in[4];
  const float* target_bbox  = (const float*)d_in[5];
  const float* target_masks = (const float*)d_in[6];
  const float* anchors      = (const float*)d_in[7];
  const float* scalers      = (const float*)d_in[8];
  float* out = (float*)d_out;

  // ws layout (floats); ~7.6 MB total
  float* ws        = (float*)d_ws;
  float* kth       = ws;                               // 200
  float* maxt      = kth    + B_N*T_N;                 // 200
  float* maxiou    = maxt   + B_N*T_N;                 // 200
  float* params    = ws + 600;                         // 16800*12
  float* tmat      = params + (size_t)NROWS*PARAM_STRIDE;   // 1,680,000
  float* pred_atan = tmat + (size_t)B_N*T_N*A_TOT;     // 16800
  float* tgt_atan  = pred_atan + NROWS;                // 200

  k_prep<<<(NROWS + 255)/256, 256, 0, stream>>>(pred_boxes, target_bbox,
                                                pred_atan, tgt_atan);
  k_score<<<B_N*T_N, 512, 0, stream>>>(cls_logits, pred_boxes, target_bbox,
                                       target_cls, anchors, pred_atan, tgt_atan,
                                       tmat, kth, maxt, maxiou);
  dim3 gAsn((A_TOT + 63)/64, B_N);                  // 132 x 2
  k_assign<<<gAsn, 64, 0, stream>>>(tmat, kth, maxt, maxiou, target_bbox,
                                    target_cls, scalers, params);
  k_write<<<2048, 256, 0, stream>>>(cls_logits, pred_boxes, mask_embs, protos,
                                    target_masks, params, out);
}